// Round 3
// baseline (153.507 us; speedup 1.0000x reference)
//
#include <hip/hip_runtime.h>
#include <math.h>

// Problem constants (reference: N=16384, D=2, H=128, fp32)
#define N_ROWS 16384
#define HDIM   128
#define NH     (N_ROWS * HDIM)   // 2097152 floats per [N,H] output
#define NH4    (NH / 4)          // 524288 float4
#define B1     512               // k1 blocks: 512*256 threads
#define K1_ITERS 4               // NH4 / (B1*256) -- compile-time trip count

// Workspace accumulators (float offsets). Zeroed by k0_init each iteration.
// r2 change: atomic accumulators + last-block finalize replace the separate
// k2 dispatch (saves k2 exec ~3.5us + inter-dispatch gap; pays ~0.8us init).
#define OFF_SY 0                 // 128 floats : S_y column accumulator
#define OFF_YN 128               // 1 float    : sum ||y||^2
#define OFF_DG 130               // 1 double   : sum diag (byte 520, 8-aligned)
#define OFF_MX 132               // 1 int      : max diag (float-as-int, vals >= 0)
#define OFF_CT 133               // 1 uint     : arrival counter
#define WS_INIT_FLOATS 136

// Native clang vector for nontemporal builtins (HIP float4 is a class type,
// rejected by __builtin_nontemporal_store -- r1 compile fix).
typedef float v4f __attribute__((ext_vector_type(4)));

__device__ __forceinline__ void nt_store4(const float4& v, float4* p) {
    v4f t = { v.x, v.y, v.z, v.w };
    __builtin_nontemporal_store(t, reinterpret_cast<v4f*>(p));
}

// Tiny init: zero the accumulators + counter. One dispatch, ~1us.
__global__ __launch_bounds__(256) void k0_init(float* __restrict__ ws) {
    const int t = threadIdx.x;
    if (t < WS_INIT_FLOATS) ws[t] = 0.0f;   // double 0.0 == two zero floats
}

// K1 fused: streaming pass + atomic partial accumulation + last-block finalize.
// bi[i][h] = in[i*256+h] + in[i*256+128+h].
// float4 index v: row = v>>5, h4 = v&31; input float4 addr = 2v-h4 (+32 dir1).
// Stride is a multiple of 32 so h4 is fixed per thread; lanes 0..31 of each
// half-wave hold one full row per iteration -> width-32 butterfly gives the
// row diag. Wave reads are contiguous 2KB spans; stores contiguous -> BW-bound
// at roofline (~58.8 MB mandatory traffic ~ 10us).
//
// Cross-block protocol: per-block partials are atomicAdd'd (device-scope by
// default on CDNA) into ws accumulators; __threadfence + counter RMW; the
// 512th arrival finalizes, reading accumulators with agent-scope atomic loads
// (bypasses any stale per-XCD L2 lines). dsum accumulates in DOUBLE so atomic
// ordering variation (<1e-9 abs of ~8.4e6) cannot move the fp32 result.
__global__ __launch_bounds__(256) void k1_fused(
    const float4* __restrict__ enc, const float4* __restrict__ dec,
    float* __restrict__ outf, float* __restrict__ ws)
{
    float4* out4 = reinterpret_cast<float4*>(outf);
    const int tid  = threadIdx.x;
    const int b    = blockIdx.x;
    const int gid0 = b * 256 + tid;
    const int stride = B1 * 256;          // 131072, multiple of 32 -> h4 fixed
    const int h4 = tid & 31;

    // ---- issue all 16 loads up front (static indices -> registers) ----
    float4 e0[K1_ITERS], e1[K1_ITERS], d0[K1_ITERS], d1[K1_ITERS];
    #pragma unroll
    for (int k = 0; k < K1_ITERS; ++k) {
        const int base = 2 * (gid0 + k * stride) - h4;
        e0[k] = enc[base];
        e1[k] = enc[base + 32];
        d0[k] = dec[base];
        d1[k] = dec[base + 32];
    }

    float4 asy = make_float4(0.f, 0.f, 0.f, 0.f);
    float ayn = 0.f, adg = 0.f, dgmx = 0.f;

    #pragma unroll
    for (int k = 0; k < K1_ITERS; ++k) {
        const int v = gid0 + k * stride;
        float4 x = make_float4(e0[k].x + e1[k].x, e0[k].y + e1[k].y,
                               e0[k].z + e1[k].z, e0[k].w + e1[k].w);
        float4 y = make_float4(d0[k].x + d1[k].x, d0[k].y + d1[k].y,
                               d0[k].z + d1[k].z, d0[k].w + d1[k].w);
        nt_store4(x, &out4[v]);            // output 0: bi_enc
        nt_store4(x, &out4[NH4 + v]);      // output 1: bi_enc (dup)
        nt_store4(y, &out4[2 * NH4 + v]);  // output 2: bi_dec

        asy.x += y.x; asy.y += y.y; asy.z += y.z; asy.w += y.w;
        ayn += y.x * y.x + y.y * y.y + y.z * y.z + y.w * y.w;

        float fx = x.x - y.x, fy = x.y - y.y, fz = x.z - y.z, fw = x.w - y.w;
        float dg = fx * fx + fy * fy + fz * fz + fw * fw;
        adg += dg;
        #pragma unroll
        for (int m = 16; m > 0; m >>= 1) dg += __shfl_xor(dg, m, 32);  // full-row diag
        dgmx = fmaxf(dgmx, dg);
    }

    // ---- block-level reduction of partials ----
    __shared__ float4 ssy[256];
    __shared__ float s_yn[256], s_dg[256], s_mx[256];
    ssy[tid] = asy; s_yn[tid] = ayn; s_dg[tid] = adg; s_mx[tid] = dgmx;
    __syncthreads();
    for (int off = 128; off > 0; off >>= 1) {
        if (tid < off) {
            s_yn[tid] += s_yn[tid + off];
            s_dg[tid] += s_dg[tid + off];
            s_mx[tid]  = fmaxf(s_mx[tid], s_mx[tid + off]);
        }
        __syncthreads();
    }

    // ---- atomic accumulation into ws (device scope) ----
    if (tid < 32) {   // column partial: thread t owns float4-column t
        float4 t = ssy[tid];
        #pragma unroll
        for (int k = 1; k < 8; ++k) {
            float4 u = ssy[tid + 32 * k];
            t.x += u.x; t.y += u.y; t.z += u.z; t.w += u.w;
        }
        atomicAdd(&ws[OFF_SY + 4 * tid + 0], t.x);
        atomicAdd(&ws[OFF_SY + 4 * tid + 1], t.y);
        atomicAdd(&ws[OFF_SY + 4 * tid + 2], t.z);
        atomicAdd(&ws[OFF_SY + 4 * tid + 3], t.w);
    }
    if (tid == 0) {
        atomicAdd(&ws[OFF_YN], s_yn[0]);
        atomicAdd(reinterpret_cast<double*>(ws + OFF_DG), (double)s_dg[0]);
        atomicMax(reinterpret_cast<int*>(ws + OFF_MX), __float_as_int(s_mx[0]));
    }
    __threadfence();        // release: this block's atomics visible before arrival
    __syncthreads();        // all threads' atomics issued+drained before counter

    __shared__ int s_last;
    if (tid == 0) {
        unsigned old = atomicAdd(reinterpret_cast<unsigned*>(ws + OFF_CT), 1u);
        s_last = (old == (unsigned)(B1 - 1));
    }
    __syncthreads();
    if (!s_last) return;

    // ================== finalize (last block only, ~1us) ==================
    __threadfence();   // acquire side
    // agent-scope atomic loads bypass stale per-XCD caches
    float syh = 0.f;
    if (tid < HDIM)
        syh = __hip_atomic_load(&ws[OFF_SY + tid], __ATOMIC_RELAXED,
                                __HIP_MEMORY_SCOPE_AGENT);
    __shared__ float red[256];
    red[tid] = syh * syh;
    __syncthreads();
    for (int off = 128; off > 0; off >>= 1) {
        if (tid < off) red[tid] += red[tid + off];
        __syncthreads();
    }

    const float  ss2   = red[0];
    const float  sumyn = __hip_atomic_load(&ws[OFF_YN], __ATOMIC_RELAXED,
                                           __HIP_MEMORY_SCOPE_AGENT);
    const double dsum  = __hip_atomic_load(reinterpret_cast<double*>(ws + OFF_DG),
                                           __ATOMIC_RELAXED, __HIP_MEMORY_SCOPE_AGENT);
    const float  dgmax = __int_as_float(
        __hip_atomic_load(reinterpret_cast<int*>(ws + OFF_MX),
                          __ATOMIC_RELAXED, __HIP_MEMORY_SCOPE_AGENT));

    // row_loss_i = 5 - sum_j dist_cl[i,j] + 10*dg_i, dist_cl >= dist_exact, so
    // row_loss_i <= 5 + ||S_y||^2/N - sumyn + 10*max_dg  << 0 for bench data
    // -> every clamped row_loss is 0 exactly. Exact fallback kept for
    // generality (never taken; reads coherent INPUTS, not cross-XCD out lines).
    const float bound = 5.f + ss2 / (float)N_ROWS - sumyn + 10.f * dgmax;
    if (bound < -1.0e4f) {
        if (tid == 0) {
            outf[3 * NH]     = 0.0f;                              // nce_loss
            outf[3 * NH + 1] = (float)(-dsum / (double)N_ROWS);   // diagonal_loss
        }
        return;
    }

    // ---- exact O(N^2 H) fallback (unreachable for Gaussian benchmark data).
    // No local arrays: recompute x on the fly so cold code cannot inflate the
    // hot path's VGPR budget. Reads enc/dec (read-only, coherent).
    {
        const float* ef = reinterpret_cast<const float*>(enc);
        const float* df = reinterpret_cast<const float*>(dec);
        __shared__ double snce[256];
        double nce = 0.0;
        for (int i = tid; i < N_ROWS; i += 256) {
            float xn = 0.f;
            for (int h = 0; h < HDIM; ++h) {
                float xh = ef[i * 256 + h] + ef[i * 256 + 128 + h];
                xn += xh * xh;
            }
            double rowsum = 0.0;
            for (int j = 0; j < N_ROWS; ++j) {
                float ynn = 0.f, xy = 0.f;
                for (int h = 0; h < HDIM; ++h) {
                    float xh = ef[i * 256 + h] + ef[i * 256 + 128 + h];
                    float yh = df[j * 256 + h] + df[j * 256 + 128 + h];
                    ynn += yh * yh; xy += xh * yh;
                }
                rowsum += (double)fmaxf(xn + ynn - 2.f * xy, 0.f);
            }
            float ynn = 0.f, xy = 0.f;
            for (int h = 0; h < HDIM; ++h) {
                float xh = ef[i * 256 + h] + ef[i * 256 + 128 + h];
                float yh = df[i * 256 + h] + df[i * 256 + 128 + h];
                ynn += yh * yh; xy += xh * yh;
            }
            const float diag = fmaxf(xn + ynn - 2.f * xy, 0.f);
            const double rl = 5.0 - rowsum + 10.0 * (double)diag;
            nce += (rl > 0.0) ? rl : 0.0;
        }
        snce[tid] = nce;
        __syncthreads();
        for (int off = 128; off > 0; off >>= 1) {
            if (tid < off) snce[tid] += snce[tid + off];
            __syncthreads();
        }
        if (tid == 0) {
            outf[3 * NH]     = (float)snce[0];
            outf[3 * NH + 1] = (float)(-dsum / (double)N_ROWS);
        }
    }
}

extern "C" void kernel_launch(void* const* d_in, const int* in_sizes, int n_in,
                              void* d_out, int out_size, void* d_ws, size_t ws_size,
                              hipStream_t stream) {
    const float4* enc = (const float4*)d_in[0];   // [16384, 2, 128] fp32
    const float4* dec = (const float4*)d_in[1];   // [16384, 2, 128] fp32
    float* out = (float*)d_out;                   // 3*NH + 2 floats
    float* ws  = (float*)d_ws;

    k0_init<<<1, 256, 0, stream>>>(ws);
    k1_fused<<<B1, 256, 0, stream>>>(enc, dec, out, ws);
}

// Round 4
// 87.980 us; speedup vs baseline: 1.7448x; 1.7448x over previous
//
#include <hip/hip_runtime.h>
#include <math.h>

// Problem constants (reference: N=16384, D=2, H=128, fp32)
#define N_ROWS 16384
#define HDIM   128
#define NH     (N_ROWS * HDIM)   // 2097152 floats per [N,H] output
#define NH4    (NH / 4)          // 524288 float4
#define B1     512               // k1 blocks: 512*256 threads
#define K1_ITERS 4               // NH4 / (B1*256) -- compile-time trip count

// Workspace layout (float offsets). Written before read; no atomics, no init.
// r3 post-mortem (this session, again): fused atomic finalize + threadfence
// = 90us serialized kernel (contended atomic RMW chains + per-wave agent-scope
// L2 writeback/invalidate). Plain per-block partial stores + tiny second
// dispatch is the verified-fastest structure. DO NOT re-introduce atomics.
#define OFF_SY1 0                      // 512*128 : per-block column sums of bi_dec
#define OFF_YN1 65536                  // 512     : per-block sum ||y||^2
#define OFF_DG1 66048                  // 512     : per-block sum (x-y)^2
#define OFF_MX1 66560                  // 512     : per-block max row diag

// Native clang vector for nontemporal builtins (HIP float4 is a class type,
// rejected by __builtin_nontemporal_store -- r1 compile fix).
typedef float v4f __attribute__((ext_vector_type(4)));

__device__ __forceinline__ void nt_store4(const float4& v, float4* p) {
    v4f t = { v.x, v.y, v.z, v.w };
    __builtin_nontemporal_store(t, reinterpret_cast<v4f*>(p));
}

// K1: streaming pass. bi[i][h] = in[i*256+h] + in[i*256+128+h].
// float4 index v: row = v>>5, h4 = v&31; input float4 addr = 2v-h4 (+32 dir1).
// Stride is a multiple of 32 so h4 is fixed per thread; lanes 0..31 of each
// half-wave hold one full row per iteration -> width-32 butterfly gives the
// row diag. Compile-time trip count (k=0..3), all 16 loads hoisted; outputs
// via nontemporal stores. BW-bound at roofline: 58.8 MB mandatory ~ 10us.
__global__ __launch_bounds__(256) void k1_stream(
    const float4* __restrict__ enc, const float4* __restrict__ dec,
    float* __restrict__ outf, float* __restrict__ ws)
{
    float4* out4 = reinterpret_cast<float4*>(outf);
    const int tid  = threadIdx.x;
    const int b    = blockIdx.x;
    const int gid0 = b * 256 + tid;
    const int stride = B1 * 256;          // 131072, multiple of 32 -> h4 fixed
    const int h4 = tid & 31;

    // ---- issue all 16 loads up front (static indices -> registers) ----
    float4 e0[K1_ITERS], e1[K1_ITERS], d0[K1_ITERS], d1[K1_ITERS];
    #pragma unroll
    for (int k = 0; k < K1_ITERS; ++k) {
        const int base = 2 * (gid0 + k * stride) - h4;
        e0[k] = enc[base];
        e1[k] = enc[base + 32];
        d0[k] = dec[base];
        d1[k] = dec[base + 32];
    }

    float4 asy = make_float4(0.f, 0.f, 0.f, 0.f);
    float ayn = 0.f, adg = 0.f, dgmx = 0.f;

    #pragma unroll
    for (int k = 0; k < K1_ITERS; ++k) {
        const int v = gid0 + k * stride;
        float4 x = make_float4(e0[k].x + e1[k].x, e0[k].y + e1[k].y,
                               e0[k].z + e1[k].z, e0[k].w + e1[k].w);
        float4 y = make_float4(d0[k].x + d1[k].x, d0[k].y + d1[k].y,
                               d0[k].z + d1[k].z, d0[k].w + d1[k].w);
        nt_store4(x, &out4[v]);            // output 0: bi_enc
        nt_store4(x, &out4[NH4 + v]);      // output 1: bi_enc (dup)
        nt_store4(y, &out4[2 * NH4 + v]);  // output 2: bi_dec

        asy.x += y.x; asy.y += y.y; asy.z += y.z; asy.w += y.w;
        ayn += y.x * y.x + y.y * y.y + y.z * y.z + y.w * y.w;

        float fx = x.x - y.x, fy = x.y - y.y, fz = x.z - y.z, fw = x.w - y.w;
        float dg = fx * fx + fy * fy + fz * fz + fw * fw;
        adg += dg;
        #pragma unroll
        for (int m = 16; m > 0; m >>= 1) dg += __shfl_xor(dg, m, 32);  // full-row diag
        dgmx = fmaxf(dgmx, dg);
    }

    __shared__ float4 ssy[256];
    __shared__ float s_yn[256], s_dg[256], s_mx[256];
    ssy[tid] = asy; s_yn[tid] = ayn; s_dg[tid] = adg; s_mx[tid] = dgmx;
    __syncthreads();
    for (int off = 128; off > 0; off >>= 1) {
        if (tid < off) {
            s_yn[tid] += s_yn[tid + off];
            s_dg[tid] += s_dg[tid + off];
            s_mx[tid]  = fmaxf(s_mx[tid], s_mx[tid + off]);
        }
        __syncthreads();
    }
    if (tid < 32) {   // column partial: thread t owns float4-columns t
        float4 t = ssy[tid];
        #pragma unroll
        for (int k = 1; k < 8; ++k) {
            float4 u = ssy[tid + 32 * k];
            t.x += u.x; t.y += u.y; t.z += u.z; t.w += u.w;
        }
        reinterpret_cast<float4*>(ws + OFF_SY1)[b * 32 + tid] = t;
    }
    if (tid == 0) {
        ws[OFF_YN1 + b] = s_yn[0];
        ws[OFF_DG1 + b] = s_dg[0];
        ws[OFF_MX1 + b] = s_mx[0];
    }
}

// K2 (1 block, 1024 threads): full finalize. Partials are 256 KB + 6 KB,
// read as independent coalesced float4 loads (single latency batch).
// row_loss_i = 5 - sum_j dist_cl[i,j] + 10*dg_i, dist_cl >= dist_exact, so
// row_loss_i <= 5 + ||S_y||^2/N - sumyn + 10*max_dg  << 0 for bench data
// -> every clamped row_loss is 0 exactly. Exact O(N^2 H) fallback kept for
// full generality (never taken).
__global__ __launch_bounds__(1024) void k2_finalize(
    const float* __restrict__ ws, float* __restrict__ outf)
{
    const int tid = threadIdx.x;
    const float4* SY1 = reinterpret_cast<const float4*>(ws + OFF_SY1);

    // --- S_y: 1024 threads = 32 col4-groups x 32 block-slices; 16 float4 each
    const int col4 = tid & 31, r = tid >> 5;
    float4 a = make_float4(0.f, 0.f, 0.f, 0.f);
    #pragma unroll
    for (int j = 0; j < 16; ++j) {
        float4 u = SY1[(r * 16 + j) * 32 + col4];
        a.x += u.x; a.y += u.y; a.z += u.z; a.w += u.w;
    }

    // --- scalars: 512 each of yn / dg / mx; one per thread (tid<512) ---
    float yn = 0.f, mx = 0.f;
    double dgd = 0.0;
    if (tid < 512) {
        yn  = ws[OFF_YN1 + tid];
        dgd = (double)ws[OFF_DG1 + tid];
        mx  = ws[OFF_MX1 + tid];
    }

    __shared__ float4 sred[1024];
    __shared__ float s_yn[1024], s_mx[1024];
    __shared__ double s_dg[1024];
    sred[tid] = a; s_yn[tid] = yn; s_mx[tid] = mx; s_dg[tid] = dgd;
    __syncthreads();
    for (int off = 512; off >= 32; off >>= 1) {
        if (tid < off) {
            float4 u = sred[tid + off];
            sred[tid].x += u.x; sred[tid].y += u.y;
            sred[tid].z += u.z; sred[tid].w += u.w;
        }
        __syncthreads();
    }
    for (int off = 512; off > 0; off >>= 1) {
        if (tid < off) {
            s_yn[tid] += s_yn[tid + off];
            s_dg[tid] += s_dg[tid + off];
            s_mx[tid]  = fmaxf(s_mx[tid], s_mx[tid + off]);
        }
        __syncthreads();
    }

    // sred[0..31] = S_y as float4. ||S_y||^2 via LDS reduce.
    __shared__ float sy[128];
    __shared__ float red[1024];
    if (tid < 32) reinterpret_cast<float4*>(sy)[tid] = sred[tid];
    __syncthreads();
    red[tid] = (tid < 128) ? sy[tid] * sy[tid] : 0.f;
    __syncthreads();
    for (int off = 512; off > 0; off >>= 1) {
        if (tid < off) red[tid] += red[tid + off];
        __syncthreads();
    }

    const float  ss2   = red[0];
    const float  sumyn = s_yn[0];
    const double dsum  = s_dg[0];
    const float  dgmax = s_mx[0];

    const float bound = 5.f + ss2 / (float)N_ROWS - sumyn + 10.f * dgmax;
    if (bound < -1.0e4f) {
        if (tid == 0) {
            outf[3 * NH]     = 0.0f;                              // nce_loss
            outf[3 * NH + 1] = (float)(-dsum / (double)N_ROWS);   // diagonal_loss
        }
        return;
    }

    // ---- exact fallback (unreachable for Gaussian benchmark data) ----
    __shared__ double snce[1024];
    const float* X = outf;            // bi_enc
    const float* Y = outf + 2 * NH;   // bi_dec
    double nce = 0.0;
    for (int i = tid; i < N_ROWS; i += 1024) {
        const float* xi = X + i * HDIM;
        float xn = 0.f;
        for (int h = 0; h < HDIM; ++h) xn += xi[h] * xi[h];
        double rowsum = 0.0;
        for (int j = 0; j < N_ROWS; ++j) {
            const float* yj = Y + j * HDIM;
            float ynn = 0.f, xy = 0.f;
            for (int h = 0; h < HDIM; ++h) { ynn += yj[h] * yj[h]; xy += xi[h] * yj[h]; }
            rowsum += (double)fmaxf(xn + ynn - 2.f * xy, 0.f);
        }
        const float* yi = Y + i * HDIM;
        float ynn = 0.f, xy = 0.f;
        for (int h = 0; h < HDIM; ++h) { ynn += yi[h] * yi[h]; xy += xi[h] * yi[h]; }
        const float diag = fmaxf(xn + ynn - 2.f * xy, 0.f);
        const double rl = 5.0 - rowsum + 10.0 * (double)diag;
        nce += (rl > 0.0) ? rl : 0.0;
    }
    snce[tid] = nce;
    __syncthreads();
    for (int off = 512; off > 0; off >>= 1) {
        if (tid < off) snce[tid] += snce[tid + off];
        __syncthreads();
    }
    if (tid == 0) {
        outf[3 * NH]     = (float)snce[0];
        outf[3 * NH + 1] = (float)(-dsum / (double)N_ROWS);
    }
}

extern "C" void kernel_launch(void* const* d_in, const int* in_sizes, int n_in,
                              void* d_out, int out_size, void* d_ws, size_t ws_size,
                              hipStream_t stream) {
    const float4* enc = (const float4*)d_in[0];   // [16384, 2, 128] fp32
    const float4* dec = (const float4*)d_in[1];   // [16384, 2, 128] fp32
    float* out = (float*)d_out;                   // 3*NH + 2 floats
    float* ws  = (float*)d_ws;

    k1_stream<<<B1, 256, 0, stream>>>(enc, dec, out, ws);
    k2_finalize<<<1, 1024, 0, stream>>>(ws, out);
}